// Round 3
// baseline (584.253 us; speedup 1.0000x reference)
//
#include <hip/hip_runtime.h>
#include <math.h>

// MoE gate: logits = h(16384x4096) @ w(64x4096)^T + bias; softmax; top-2;
// renormalize. Output: [topk_w (16384x2 f32) ; topk_idx (16384x2 as f32)].
//
// R3 changes vs R2 (which was LDS-pipe-bound + 8-way bank conflicts):
//  * 8 rows/thread (was 4): per chunk, LDS/CU = 3072 cyc < FMA/SIMD = 4096.
//  * XOR-swizzled LDS layout lwq[j*512 + kq*16 + (g^(kq&15))] (float4 slots):
//    reads AND staging writes land 8 lanes per bank-quad at distinct
//    addresses = stride-1-equivalent, zero conflicts. (R2's pad-132 had
//    ks*32%32==0 and 8*132%32==0 -> 8-way collisions, 5.1e7 conflict cyc.)
//  * grid 512 WGs = 2 WG/CU; inter-WG overlap hides staging latency.
//
// WG = 256 threads = 16 shard-groups(g) x 4 k-slices(ks) x 4 waves(rg).
// Thread tile = 8 rows x 4 shards (shard = g*4+j). acc[8][4] in VGPRs.
// Epilogue fused in-wave: shfl_xor ks-reduce (16,32), per-thread top-2,
// index-tie-broken top-2 merge across g (1,2,4,8); softmax Z cancels.

#define HIDDEN   4096
#define NSHARD   64
#define B_ROWS   16384
#define WGT      256
#define ROWS_WG  32
#define RPT      8               // rows per thread
#define KC       128
#define NCHUNK   (HIDDEN / KC)   // 32

__global__ __launch_bounds__(WGT, 4)
void gate_kernel(const float* __restrict__ h,
                 const float* __restrict__ w,
                 const float* __restrict__ bias,
                 float* __restrict__ out)
{
    __shared__ float4 lwq[2048];       // 64 shards x 32 float4 = 32 KB

    const int tid = threadIdx.x;
    const int g   = tid & 15;          // shard group: shards g*4+j
    const int ks  = (tid >> 4) & 3;    // k-slice (32 floats of each chunk)
    const int rg  = tid >> 6;          // wave id -> row group (8 rows)
    const int row0 = blockIdx.x * ROWS_WG + rg * RPT;

    const float* __restrict__ hbase = h + (size_t)row0 * HIDDEN;
    const float4* __restrict__ wq   = (const float4*)w;   // row stride 1024

    float acc[RPT][4];
#pragma unroll
    for (int r = 0; r < RPT; ++r)
#pragma unroll
        for (int j = 0; j < 4; ++j) acc[r][j] = 0.0f;

    for (int c = 0; c < NCHUNK; ++c) {
        __syncthreads();               // prior-chunk readers done
        // ---- stage w[0..63][c*128 .. +128) -> LDS, swizzled ----
#pragma unroll
        for (int t = 0; t < 8; ++t) {
            const int idx = t * WGT + tid;      // 0..2047
            const int e   = idx >> 5;           // shard
            const int kq  = idx & 31;           // float4 within chunk
            const float4 v = wq[(size_t)e * (HIDDEN / 4) + c * 32 + kq];
            const int j  = e & 3;
            const int ge = e >> 2;
            lwq[j * 512 + kq * 16 + (ge ^ (kq & 15))] = v;
        }
        __syncthreads();

        // ---- compute: 8 float4 steps over this thread's 32-float slice ----
#pragma unroll
        for (int step = 0; step < 8; ++step) {
            const int kq  = ks * 8 + step;
            const int kin = c * KC + kq * 4;
            float4 hv[RPT];
#pragma unroll
            for (int r = 0; r < RPT; ++r)
                hv[r] = *(const float4*)(hbase + (size_t)r * HIDDEN + kin);
            const int gx = g ^ (kq & 15);
#pragma unroll
            for (int j = 0; j < 4; ++j) {
                const float4 wv = lwq[j * 512 + kq * 16 + gx];
#pragma unroll
                for (int r = 0; r < RPT; ++r) {
                    acc[r][j] = fmaf(hv[r].x, wv.x, acc[r][j]);
                    acc[r][j] = fmaf(hv[r].y, wv.y, acc[r][j]);
                    acc[r][j] = fmaf(hv[r].z, wv.z, acc[r][j]);
                    acc[r][j] = fmaf(hv[r].w, wv.w, acc[r][j]);
                }
            }
        }
    }

    // ---- reduce over the 4 k-slices (lane bits 4,5) ----
#pragma unroll
    for (int m = 16; m <= 32; m <<= 1)
#pragma unroll
        for (int r = 0; r < RPT; ++r)
#pragma unroll
            for (int j = 0; j < 4; ++j)
                acc[r][j] += __shfl_xor(acc[r][j], m, 64);

    // ---- bias + per-thread top-2 over 4 shards (ascending idx) ----
    const float4 bv = *(const float4*)(bias + g * 4);
    float m1[RPT], m2[RPT];
    int   i1[RPT], i2[RPT];
#pragma unroll
    for (int r = 0; r < RPT; ++r) {
        float v0 = acc[r][0] + bv.x, v1 = acc[r][1] + bv.y;
        float v2 = acc[r][2] + bv.z, v3 = acc[r][3] + bv.w;
        float a1 = v0, a2 = -INFINITY; int b1 = g * 4, b2 = 0;
        if (v1 > a1)      { a2 = a1; b2 = b1; a1 = v1; b1 = g * 4 + 1; }
        else              { a2 = v1; b2 = g * 4 + 1; }
        if (v2 > a1)      { a2 = a1; b2 = b1; a1 = v2; b1 = g * 4 + 2; }
        else if (v2 > a2) { a2 = v2; b2 = g * 4 + 2; }
        if (v3 > a1)      { a2 = a1; b2 = b1; a1 = v3; b1 = g * 4 + 3; }
        else if (v3 > a2) { a2 = v3; b2 = g * 4 + 3; }
        m1[r] = a1; i1[r] = b1; m2[r] = a2; i2[r] = b2;
    }

    // ---- merge top-2 across the 16 shard-groups (lane bits 0..3) ----
#pragma unroll
    for (int m = 1; m <= 8; m <<= 1) {
#pragma unroll
        for (int r = 0; r < RPT; ++r) {
            const float o1 = __shfl_xor(m1[r], m, 64);
            const int   q1 = __shfl_xor(i1[r], m, 64);
            const float o2 = __shfl_xor(m2[r], m, 64);
            const int   q2 = __shfl_xor(i2[r], m, 64);
            const bool take = (o1 > m1[r]) || (o1 == m1[r] && q1 < i1[r]);
            const float w1 = take ? o1 : m1[r]; const int w1i = take ? q1 : i1[r];
            const float l1 = take ? m1[r] : o1; const int l1i = take ? i1[r] : q1;
            const float s2 = take ? o2 : m2[r]; const int s2i = take ? q2 : i2[r];
            const bool t2 = (l1 > s2) || (l1 == s2 && l1i < s2i);
            m1[r] = w1; i1[r] = w1i;
            m2[r] = t2 ? l1 : s2; i2[r] = t2 ? l1i : s2i;
        }
    }

    // ---- write: softmax Z cancels; w1 = 1/(1+e^{l2-l1}), w2 = 1-w1 ----
    if ((tid & 63) == 0) {
        float* __restrict__ oidx = out + 2 * B_ROWS;
#pragma unroll
        for (int r = 0; r < RPT; ++r) {
            const int row = row0 + r;
            const float ed  = expf(m2[r] - m1[r]);   // <= 1
            const float inv = 1.0f / (1.0f + ed);
            out[2 * row + 0] = inv;
            out[2 * row + 1] = ed * inv;
            oidx[2 * row + 0] = (float)i1[r];
            oidx[2 * row + 1] = (float)i2[r];
        }
    }
}

extern "C" void kernel_launch(void* const* d_in, const int* in_sizes, int n_in,
                              void* d_out, int out_size, void* d_ws, size_t ws_size,
                              hipStream_t stream)
{
    const float* h    = (const float*)d_in[0];
    const float* wt   = (const float*)d_in[1];
    const float* bias = (const float*)d_in[2];
    float* out = (float*)d_out;

    gate_kernel<<<dim3(B_ROWS / ROWS_WG), dim3(WGT), 0, stream>>>(h, wt, bias, out);
}

// Round 4
// 464.395 us; speedup vs baseline: 1.2581x; 1.2581x over previous
//
#include <hip/hip_runtime.h>
#include <hip/hip_bf16.h>
#include <math.h>

// MoE gate: logits = h(16384x4096) @ w(64x4096)^T + bias; softmax; top-2;
// renormalize. Output: [topk_w (16384x2 f32) ; topk_idx (16384x2 as f32)].
//
// R4: abandon f32 VALU (floor 54.6 us, and the allocator keeps pinning
// 64 VGPR + spilling). Split-precision bf16 MFMA:
//   h = hi + lo (bf16 RN; residual exact in f32, |err| <= 2^-18 |h|),
//   w likewise (precomputed to d_ws by wsplit_kernel).
//   logits = hihi + (hilo + lohi + lolo), cross terms in a separate f32
//   accumulator so 2^-9-scale terms aren't swamped. Logit err ~1.5e-6 =
//   same class as the f32 kernels that passed R1-R3.
// Floor: h stream 256 MB / 6.3 TB/s = 41 us; MFMA = 4 x 8.6 GF = ~4 us.
//
// gate_kernel: WG=256 (4 waves), WG owns 16 rows, wave q owns K in
// [q*1024,+1024). Grid 1024 = 4 WG/CU = 16 waves/CU. No K-loop barriers.
// A frags load DIRECT from global h (m=lane&15 row, k=quad*8+j: the two
// dwordx4 of a step consume whole 128B lines); B frags from L2-resident
// w_hi/w_lo. Epilogue: LDS partial dump (stride 68: conflict-free, 16B
// aligned), 1 barrier, 4-way reduce + bias + top-2 + softmax-cancel.

#define HIDDEN 4096
#define NSHARD 64
#define B_ROWS 16384

typedef short bf16x8 __attribute__((ext_vector_type(8)));
typedef float f32x4  __attribute__((ext_vector_type(4)));

__device__ __forceinline__ unsigned short f32_to_bf16_rn(float f) {
    __hip_bfloat16 h = __float2bfloat16(f);          // round-to-nearest
    return *reinterpret_cast<unsigned short*>(&h);
}
__device__ __forceinline__ float bf16_bits_to_f32(unsigned short u) {
    union { unsigned int i; float f; } v; v.i = ((unsigned int)u) << 16;
    return v.f;
}

// ---- kernel 1: split w into bf16 hi/lo (d_ws rewritten every launch) ----
__global__ __launch_bounds__(256)
void wsplit_kernel(const float* __restrict__ w,
                   unsigned short* __restrict__ w_hi,
                   unsigned short* __restrict__ w_lo)
{
    const int idx = (blockIdx.x * 256 + threadIdx.x) * 4;
    const float4 v = *(const float4*)(w + idx);
    const float a[4] = {v.x, v.y, v.z, v.w};
    ushort4 hi, lo;
    unsigned short hb;
    hb = f32_to_bf16_rn(a[0]); hi.x = hb; lo.x = f32_to_bf16_rn(a[0] - bf16_bits_to_f32(hb));
    hb = f32_to_bf16_rn(a[1]); hi.y = hb; lo.y = f32_to_bf16_rn(a[1] - bf16_bits_to_f32(hb));
    hb = f32_to_bf16_rn(a[2]); hi.z = hb; lo.z = f32_to_bf16_rn(a[2] - bf16_bits_to_f32(hb));
    hb = f32_to_bf16_rn(a[3]); hi.w = hb; lo.w = f32_to_bf16_rn(a[3] - bf16_bits_to_f32(hb));
    *(ushort4*)(w_hi + idx) = hi;
    *(ushort4*)(w_lo + idx) = lo;
}

// ---- kernel 2: the gate ----
__global__ __launch_bounds__(256)
void gate_kernel(const float* __restrict__ h,
                 const unsigned short* __restrict__ w_hi,
                 const unsigned short* __restrict__ w_lo,
                 const float* __restrict__ bias,
                 float* __restrict__ out)
{
    __shared__ float lsum[4][16][68];   // [wave][row][shard], pad 68

    const int tid  = threadIdx.x;
    const int lane = tid & 63;
    const int q    = tid >> 6;          // wave id = K quarter
    const int m    = lane & 15;         // A row within tile / B shard within tile
    const int quad = lane >> 4;         // k-subgroup: k = quad*8 + j
    const int row0 = blockIdx.x * 16;

    const float* __restrict__ aptr =
        h + (size_t)(row0 + m) * HIDDEN + q * 1024 + quad * 8;
    const size_t boff = (size_t)m * HIDDEN + q * 1024 + quad * 8;

    f32x4 acch[4], accx[4];             // [shard tile j]: hihi / cross terms
#pragma unroll
    for (int j = 0; j < 4; ++j) {
        acch[j] = (f32x4)0.0f;
        accx[j] = (f32x4)0.0f;
    }

    for (int step = 0; step < 32; ++step) {
        const float4 a0 = *(const float4*)(aptr + step * 32);
        const float4 a1 = *(const float4*)(aptr + step * 32 + 4);
        const float av[8] = {a0.x, a0.y, a0.z, a0.w, a1.x, a1.y, a1.z, a1.w};
        bf16x8 ahi, alo;
#pragma unroll
        for (int i = 0; i < 8; ++i) {
            const unsigned short hb = f32_to_bf16_rn(av[i]);
            ahi[i] = (short)hb;
            alo[i] = (short)f32_to_bf16_rn(av[i] - bf16_bits_to_f32(hb));
        }
#pragma unroll
        for (int j = 0; j < 4; ++j) {
            const bf16x8 bh = *(const bf16x8*)(w_hi + boff + (size_t)j * 16 * HIDDEN + step * 32);
            const bf16x8 bl = *(const bf16x8*)(w_lo + boff + (size_t)j * 16 * HIDDEN + step * 32);
            acch[j] = __builtin_amdgcn_mfma_f32_16x16x32_bf16(ahi, bh, acch[j], 0, 0, 0);
            accx[j] = __builtin_amdgcn_mfma_f32_16x16x32_bf16(alo, bh, accx[j], 0, 0, 0);
            accx[j] = __builtin_amdgcn_mfma_f32_16x16x32_bf16(ahi, bl, accx[j], 0, 0, 0);
            accx[j] = __builtin_amdgcn_mfma_f32_16x16x32_bf16(alo, bl, accx[j], 0, 0, 0);
        }
    }

    // C/D layout (m89-verified): col = lane&15 (shard), row = quad*4 + reg.
#pragma unroll
    for (int j = 0; j < 4; ++j)
#pragma unroll
        for (int p = 0; p < 4; ++p)
            lsum[q][quad * 4 + p][j * 16 + m] = acch[j][p] + accx[j][p];

    __syncthreads();

    // ---- reduce 4 K-quarters + bias; fused top-2 ----
    const int row = tid >> 4;           // 0..15
    const int s   = tid & 15;           // shard group: shards s*4..s*4+3
    float4 vs = *(const float4*)&lsum[0][row][s * 4];
    {
        const float4 v1 = *(const float4*)&lsum[1][row][s * 4];
        const float4 v2 = *(const float4*)&lsum[2][row][s * 4];
        const float4 v3 = *(const float4*)&lsum[3][row][s * 4];
        vs.x += v1.x + v2.x + v3.x;
        vs.y += v1.y + v2.y + v3.y;
        vs.z += v1.z + v2.z + v3.z;
        vs.w += v1.w + v2.w + v3.w;
    }
    const float4 bv = *(const float4*)(bias + s * 4);
    const float v0 = vs.x + bv.x, v1 = vs.y + bv.y;
    const float v2 = vs.z + bv.z, v3 = vs.w + bv.w;

    // per-thread top-2 over 4 shards (ascending idx: first-occurrence ties)
    float m1 = v0, m2 = -INFINITY;
    int   i1 = s * 4, i2 = 0;
    if (v1 > m1)      { m2 = m1; i2 = i1; m1 = v1; i1 = s * 4 + 1; }
    else              { m2 = v1; i2 = s * 4 + 1; }
    if (v2 > m1)      { m2 = m1; i2 = i1; m1 = v2; i1 = s * 4 + 2; }
    else if (v2 > m2) { m2 = v2; i2 = s * 4 + 2; }
    if (v3 > m1)      { m2 = m1; i2 = i1; m1 = v3; i1 = s * 4 + 3; }
    else if (v3 > m2) { m2 = v3; i2 = s * 4 + 3; }

    // merge across the 16 shard-groups (lane bits 0..3), index tie-break
#pragma unroll
    for (int msk = 1; msk <= 8; msk <<= 1) {
        const float o1 = __shfl_xor(m1, msk, 64);
        const int   q1 = __shfl_xor(i1, msk, 64);
        const float o2 = __shfl_xor(m2, msk, 64);
        const int   q2 = __shfl_xor(i2, msk, 64);
        const bool take = (o1 > m1) || (o1 == m1 && q1 < i1);
        const float w1 = take ? o1 : m1; const int w1i = take ? q1 : i1;
        const float l1 = take ? m1 : o1; const int l1i = take ? i1 : q1;
        const float s2 = take ? o2 : m2; const int s2i = take ? q2 : i2;
        const bool t2 = (l1 > s2) || (l1 == s2 && l1i < s2i);
        m1 = w1; i1 = w1i;
        m2 = t2 ? l1 : s2; i2 = t2 ? l1i : s2i;
    }

    if (s == 0) {
        const int orow = row0 + row;
        const float ed  = expf(m2 - m1);      // softmax Z cancels
        const float inv = 1.0f / (1.0f + ed);
        out[2 * orow + 0] = inv;
        out[2 * orow + 1] = ed * inv;
        float* __restrict__ oidx = out + 2 * B_ROWS;
        oidx[2 * orow + 0] = (float)i1;
        oidx[2 * orow + 1] = (float)i2;
    }
}

extern "C" void kernel_launch(void* const* d_in, const int* in_sizes, int n_in,
                              void* d_out, int out_size, void* d_ws, size_t ws_size,
                              hipStream_t stream)
{
    const float* h    = (const float*)d_in[0];
    const float* wt   = (const float*)d_in[1];
    const float* bias = (const float*)d_in[2];
    float* out = (float*)d_out;

    unsigned short* w_hi = (unsigned short*)d_ws;                    // 512 KB
    unsigned short* w_lo = w_hi + (size_t)NSHARD * HIDDEN;           // 512 KB

    wsplit_kernel<<<dim3(NSHARD * HIDDEN / 1024), dim3(256), 0, stream>>>(wt, w_hi, w_lo);
    gate_kernel<<<dim3(B_ROWS / 16), dim3(256), 0, stream>>>(h, w_hi, w_lo, bias, out);
}